// Round 1
// baseline (218.781 us; speedup 1.0000x reference)
//
#include <hip/hip_runtime.h>

// y = W @ x + bias, W in COO (rows sorted), fp32.
// R6: latency attack. (1) Both __syncthreads() replaced by lgkmcnt-only
// barriers (raw s_barrier + manual s_waitcnt lgkmcnt(0)) so streaming
// global loads and x-gathers stay in flight across the barrier — hipcc's
// __syncthreads emits a full vmcnt(0) drain that serialized the whole
// per-wave memory pipeline (VALUBusy was 5.4%, VGPR=28 => compiler had
// serialized the loads). (2) CHUNK 8->16 doubles per-wave MLP; registers
// forced live across the barrier. (3) Load order: cols first, then vals,
// then rows; zero-LDS overlaps cols latency; gathers issue with v/r still
// in flight.

constexpr int       CHUNK = 16;                       // nnz per thread
constexpr int       BLOCK = 256;
constexpr long long SPAN  = (long long)BLOCK * CHUNK; // 4096 nnz per block
constexpr int       RMAX  = 1024;                     // LDS acc slots (4 KB)

typedef float vfloat4 __attribute__((ext_vector_type(4)));
typedef int   vint4   __attribute__((ext_vector_type(4)));

__global__ void init_y_bias(const float* __restrict__ bias,
                            float* __restrict__ y, int n) {
    int i = blockIdx.x * blockDim.x + threadIdx.x;
    if (i < n) y[i] = bias[i];
}

__device__ __forceinline__ void lds_add(float* p, float v) {
    // workgroup-scope relaxed fp add -> ds_add_f32 (no TCC involvement)
    __hip_atomic_fetch_add(p, v, __ATOMIC_RELAXED, __HIP_MEMORY_SCOPE_WORKGROUP);
}

// Barrier that waits ONLY on LDS/SMEM ops (lgkmcnt), leaving global/buffer
// loads (vmcnt) in flight across the barrier. __syncthreads() would drain
// vmcnt(0) and serialize the streaming pipeline.
__device__ __forceinline__ void barrier_lds_only() {
    __builtin_amdgcn_sched_barrier(0);
    asm volatile("s_waitcnt lgkmcnt(0)" ::: "memory");
    __builtin_amdgcn_s_barrier();
    __builtin_amdgcn_sched_barrier(0);
}

__global__ __launch_bounds__(BLOCK) void spmv_coo_lds(
        const float* __restrict__ vals,
        const float* __restrict__ x,
        const int*   __restrict__ rows,
        const int*   __restrict__ cols,
        const float* __restrict__ bias,
        float*       __restrict__ y,
        long long nnz) {
    __shared__ float acc[RMAX];
    const int tid = threadIdx.x;
    const long long b0 = (long long)blockIdx.x * SPAN;
    if (b0 >= nnz) return;                       // whole block exits uniformly
    const long long bend = (b0 + SPAN < nnz) ? (b0 + SPAN) : nnz;
    const bool full = (b0 + SPAN) <= nnz;        // block-uniform

    // row-range bounds: scalar loads, issued early (lgkm-tracked s_load)
    const int r0 = rows[b0];
    const int rl = rows[bend - 1];

    float v[CHUNK]; int r[CHUNK]; int c[CHUNK]; float g[CHUNK];
    const long long i0 = b0 + (long long)tid * CHUNK;

    // ---- 1) issue ALL streaming loads: cols first (gathers depend on
    //         them), then vals, then rows ----
    if (full) {
        const vint4*   c4 = reinterpret_cast<const vint4*>(cols + i0);
        const vfloat4* v4 = reinterpret_cast<const vfloat4*>(vals + i0);
        const vint4*   r4 = reinterpret_cast<const vint4*>(rows + i0);
        #pragma unroll
        for (int q = 0; q < CHUNK / 4; ++q) {
            vint4 cc = __builtin_nontemporal_load(c4 + q);
            #pragma unroll
            for (int j = 0; j < 4; ++j) c[4*q+j] = cc[j];
        }
        #pragma unroll
        for (int q = 0; q < CHUNK / 4; ++q) {
            vfloat4 vv = __builtin_nontemporal_load(v4 + q);
            #pragma unroll
            for (int j = 0; j < 4; ++j) v[4*q+j] = vv[j];
        }
        #pragma unroll
        for (int q = 0; q < CHUNK / 4; ++q) {
            vint4 rr = __builtin_nontemporal_load(r4 + q);
            #pragma unroll
            for (int j = 0; j < 4; ++j) r[4*q+j] = rr[j];
        }
    }

    // ---- 2) zero LDS while cols loads are in flight ----
    #pragma unroll
    for (int i = tid; i < RMAX; i += BLOCK) acc[i] = 0.f;

    // ---- 3) issue gathers: waits vmcnt only down to the cols loads;
    //         vals/rows stay in flight ----
    if (full) {
        #pragma unroll
        for (int k = 0; k < CHUNK; ++k) g[k] = x[c[k]];
    }

    const int range = rl - r0 + 1;

    // ---- 4) barrier WITHOUT vmcnt drain: zero-stores visible, all
    //         global loads (v, r, g) still in flight ----
    barrier_lds_only();

    if (range <= RMAX) {
        if (full) {
            int   cur = r[0];
            float sum = v[0] * g[0];
            #pragma unroll
            for (int k = 1; k < CHUNK; ++k) {
                if (r[k] != cur) {               // row boundary: flush run
                    lds_add(&acc[cur - r0], sum);
                    cur = r[k];
                    sum = 0.f;
                }
                sum += v[k] * g[k];
            }
            lds_add(&acc[cur - r0], sum);
        } else if (i0 < bend) {
            // scalar partial-block path (only possibly the last block)
            int   cur = rows[i0];
            float sum = 0.f;
            long long kend = (i0 + CHUNK < bend) ? (i0 + CHUNK) : bend;
            for (long long k = i0; k < kend; ++k) {
                int rk = rows[k];
                if (rk != cur) { lds_add(&acc[cur - r0], sum); sum = 0.f; cur = rk; }
                sum += vals[k] * x[cols[k]];
            }
            lds_add(&acc[cur - r0], sum);
        }

        // LDS atomics are lgkm-tracked; vmcnt need not drain here either
        barrier_lds_only();

        // ---- coalesced epilogue: interior rows exclusively owned ----
        for (int i = tid; i < range; i += BLOCK) {
            int   rr = r0 + i;
            float a  = acc[i];
            if (rr == r0 || rr == rl) {
                if (a != 0.f) atomicAdd(&y[rr], a);  // may span block boundary
            } else {
                y[rr] = bias[rr] + a;                // plain coalesced store
            }
        }
    } else {
        // pathological row-gap fallback: per-thread global atomics
        // (block-uniform branch => no divergent-barrier hazard)
        if (i0 < bend) {
            if (full) {
                int   cur = r[0];
                float sum = v[0] * g[0];
                #pragma unroll
                for (int k = 1; k < CHUNK; ++k) {
                    if (r[k] != cur) { atomicAdd(&y[cur], sum); sum = 0.f; cur = r[k]; }
                    sum += v[k] * g[k];
                }
                atomicAdd(&y[cur], sum);
            } else {
                int   cur = rows[i0];
                float sum = 0.f;
                long long kend = (i0 + CHUNK < bend) ? (i0 + CHUNK) : bend;
                for (long long k = i0; k < kend; ++k) {
                    int rk = rows[k];
                    if (rk != cur) { atomicAdd(&y[cur], sum); sum = 0.f; cur = rk; }
                    sum += vals[k] * x[cols[k]];
                }
                atomicAdd(&y[cur], sum);
            }
        }
    }
}

extern "C" void kernel_launch(void* const* d_in, const int* in_sizes, int n_in,
                              void* d_out, int out_size, void* d_ws, size_t ws_size,
                              hipStream_t stream) {
    const float* vals = (const float*)d_in[0];
    const float* x    = (const float*)d_in[1];
    const float* bias = (const float*)d_in[2];
    const int*   rows = (const int*)d_in[3];
    const int*   cols = (const int*)d_in[4];
    float* y = (float*)d_out;

    const long long nnz = in_sizes[0];
    const int n_rows    = in_sizes[2];   // len(bias) == n_rows

    // 1) y = bias (covers empty gap-rows + rows receiving boundary atomics)
    {
        int threads = 256;
        int blocks  = (n_rows + threads - 1) / threads;
        init_y_bias<<<blocks, threads, 0, stream>>>(bias, y, n_rows);
    }

    // 2) block-local LDS-accumulated COO reduce
    {
        long long blocks = (nnz + SPAN - 1) / SPAN;
        spmv_coo_lds<<<(int)blocks, BLOCK, 0, stream>>>(
            vals, x, rows, cols, bias, y, nnz);
    }
}